// Round 6
// baseline (290.133 us; speedup 1.0000x reference)
//
#include <hip/hip_runtime.h>

#define F 4096          // feature dim (S_DIM == HID == A_DIM)
#define NE 44
#define NN 14
#define KB 8            // k-split factor
#define KC 512          // k-chunk width per block
#define KSTEP 32        // k per pass (8 k-lanes x float4)
#define NPASS 16        // KC / KSTEP
#define YPART 57344     // 14*4096, one partial Y buffer
#define H1SZ 180224     // 44*4096

// deterministic edge list from reference _edge_list()
__device__ constexpr int SRC[NE] = {
    0,1,2,3,4,5,6,7,8,9,10,11,12,13,          // fwd ring
    1,2,3,4,5,6,7,8,9,10,11,12,13,0,          // rev ring
    0,1,2,3,4,5,6,7,8,9,10,11,12,13,          // skip-2 ring
    0,7};
__device__ constexpr int DST[NE] = {
    1,2,3,4,5,6,7,8,9,10,11,12,13,0,
    0,1,2,3,4,5,6,7,8,9,10,11,12,13,
    2,3,4,5,6,7,8,9,10,11,12,13,0,1,
    7,0};
// deg: 3 everywhere except nodes 0 and 7 (4)
__device__ constexpr float INVDEG[NN] = {
    0.25f, 1.f/3.f, 1.f/3.f, 1.f/3.f, 1.f/3.f, 1.f/3.f, 1.f/3.f,
    0.25f, 1.f/3.f, 1.f/3.f, 1.f/3.f, 1.f/3.f, 1.f/3.f, 1.f/3.f};

// ---------------- prep: A = node2(edge_features) -------------------------
__global__ __launch_bounds__(256) void prep_x_k(const float* __restrict__ x,
                                                float* __restrict__ Aout) {
    int f = blockIdx.x * 256 + threadIdx.x;   // 16 blocks cover 4096
    float s[NN];
#pragma unroll
    for (int n = 0; n < NN; ++n) s[n] = 0.f;
#pragma unroll
    for (int e = 0; e < NE; ++e) s[DST[e]] += x[e * F + f];
    float node[NN];
#pragma unroll
    for (int n = 0; n < NN; ++n) node[n] = s[n] * INVDEG[n];
    float n2[NN];
#pragma unroll
    for (int n = 0; n < NN; ++n) n2[n] = 0.f;
#pragma unroll
    for (int e = 0; e < NE; ++e) n2[DST[e]] += node[SRC[e]];
#pragma unroll
    for (int m = 0; m < NN; ++m) Aout[m * F + f] = n2[m];
}

// inner layers: edge feat = leaky_relu(0.5*(Y[src]+Y[dst]) + b), Y = sum of KB partials
__device__ __forceinline__ void prep_col(const float* __restrict__ Yp,
                                         const float* __restrict__ b,
                                         float* __restrict__ Aout, int f) {
    float y[NN];
#pragma unroll
    for (int m = 0; m < NN; ++m) {
        float s = 0.f;
#pragma unroll
        for (int kb = 0; kb < KB; ++kb) s += Yp[kb * YPART + m * F + f];
        y[m] = s;
    }
    float bias = b[f];
    float s[NN];
#pragma unroll
    for (int n = 0; n < NN; ++n) s[n] = 0.f;
#pragma unroll
    for (int e = 0; e < NE; ++e) {
        float eh = 0.5f * (y[SRC[e]] + y[DST[e]]) + bias;
        eh = eh > 0.f ? eh : 0.01f * eh;      // leaky_relu(0.01)
        s[DST[e]] += eh;
    }
    float node[NN];
#pragma unroll
    for (int n = 0; n < NN; ++n) node[n] = s[n] * INVDEG[n];
    float n2[NN];
#pragma unroll
    for (int n = 0; n < NN; ++n) n2[n] = 0.f;
#pragma unroll
    for (int e = 0; e < NE; ++e) n2[DST[e]] += node[SRC[e]];
#pragma unroll
    for (int m = 0; m < NN; ++m) Aout[m * F + f] = n2[m];
}

__global__ __launch_bounds__(256) void prep2_k(const float* __restrict__ Yp1,
                                               const float* __restrict__ b1,
                                               float* __restrict__ A1,
                                               const float* __restrict__ Yp2,
                                               const float* __restrict__ b2,
                                               float* __restrict__ A2) {
    int bx = blockIdx.x;
    if (bx < 16) {
        prep_col(Yp1, b1, A1, bx * 256 + threadIdx.x);
    } else {
        prep_col(Yp2, b2, A2, (bx - 16) * 256 + threadIdx.x);
    }
}

// ---------------- GEMM: Y[m][n] = sum_k A[m][k] * W[n][k] ----------------
// Lane mapping: l = (row l>>3, k-slice l&7). Wave = 8 W-rows, k split 8-way.
// acc[14] per lane (one row) -> whole pass batch (1 W + 14 A float4) fits in
// regs -> one waitcnt per pass. 3-level butterfly (vs 6). Per branch:
// 1024 blocks = nb(128 row-blocks of 32) x kb(8 chunks of KC=512).
__global__ __launch_bounds__(256) void gemm2_k(const float* __restrict__ A1,
                                               const float* __restrict__ W1,
                                               float* __restrict__ Y1,
                                               const float* __restrict__ A2,
                                               const float* __restrict__ W2,
                                               float* __restrict__ Y2) {
    int bx = blockIdx.x;
    const float* A = A1; const float* W = W1; float* Y = Y1;
    if (bx >= 1024) { A = A2; W = W2; Y = Y2; bx -= 1024; }
    const int kb = bx & (KB - 1);   // k chunk (512 wide)
    const int nb = bx >> 3;         // 128 row-blocks of 32
    const int w  = threadIdx.x >> 6;
    const int l  = threadIdx.x & 63;
    const int row = nb * 32 + w * 8 + (l >> 3);  // this lane's W row
    const int kl  = (l & 7) * 4;                 // k offset within pass
    const int k0  = kb * KC;

    const float* Wrow = W + (size_t)row * F;

    float acc[NN];
#pragma unroll
    for (int m = 0; m < NN; ++m) acc[m] = 0.f;

#pragma unroll 2
    for (int p = 0; p < NPASS; ++p) {
        const int kq = k0 + p * KSTEP + kl;
        float4 wv = *(const float4*)(Wrow + kq);
        float4 a[NN];
#pragma unroll
        for (int m = 0; m < NN; ++m)
            a[m] = *(const float4*)(A + m * F + kq);
#pragma unroll
        for (int m = 0; m < NN; ++m)
            acc[m] += wv.x * a[m].x + wv.y * a[m].y +
                      wv.z * a[m].z + wv.w * a[m].w;
    }

    // 3-level butterfly over the 8 k-lanes of this row
#pragma unroll
    for (int m = 0; m < NN; ++m) {
        float v = acc[m];
        v += __shfl_xor(v, 1);
        v += __shfl_xor(v, 2);
        v += __shfl_xor(v, 4);
        acc[m] = v;
    }
    if ((l & 7) == 0) {
#pragma unroll
        for (int m = 0; m < NN; ++m)
            Y[kb * YPART + m * F + row] = acc[m];
    }
}

// ---------------- final: h1 edge expansion + h2 tiny GEMV ----------------
__global__ __launch_bounds__(256) void final_k(const float* __restrict__ Ypa5,
                                               const float* __restrict__ ba5,
                                               const float* __restrict__ Av2,
                                               const float* __restrict__ Wv5,
                                               const float* __restrict__ bv5,
                                               float* __restrict__ out) {
    __shared__ float red[NN][257];
    if (blockIdx.x < 176) {
        int idx4 = (blockIdx.x * 256 + threadIdx.x) * 4;  // 44*4096 elements
        int e = idx4 >> 12, f = idx4 & 4095;
        int se = SRC[e], de = DST[e];
        float4 ys = make_float4(0.f, 0.f, 0.f, 0.f);
        float4 yd = make_float4(0.f, 0.f, 0.f, 0.f);
#pragma unroll
        for (int kb = 0; kb < KB; ++kb) {
            float4 s = *(const float4*)(Ypa5 + kb * YPART + se * F + f);
            float4 d = *(const float4*)(Ypa5 + kb * YPART + de * F + f);
            ys.x += s.x; ys.y += s.y; ys.z += s.z; ys.w += s.w;
            yd.x += d.x; yd.y += d.y; yd.z += d.z; yd.w += d.w;
        }
        float4 bb = *(const float4*)(ba5 + f);
        float4 o;
        o.x = 0.5f * (ys.x + yd.x) + bb.x;
        o.y = 0.5f * (ys.y + yd.y) + bb.y;
        o.z = 0.5f * (ys.z + yd.z) + bb.z;
        o.w = 0.5f * (ys.w + yd.w) + bb.w;
        *(float4*)(out + idx4) = o;
    } else {
        // y[n] = dot(Av2[n], Wv5); h2[e] = 0.5*(y[src]+y[dst]) + bv5
        int t = threadIdx.x;
        float acc[NN];
#pragma unroll
        for (int m = 0; m < NN; ++m) acc[m] = 0.f;
        for (int f = t; f < F; f += 256) {
            float wv = Wv5[f];
#pragma unroll
            for (int m = 0; m < NN; ++m) acc[m] += Av2[m * F + f] * wv;
        }
#pragma unroll
        for (int m = 0; m < NN; ++m) red[m][t] = acc[m];
        __syncthreads();
        for (int s = 128; s > 0; s >>= 1) {
            if (t < s) {
#pragma unroll
                for (int m = 0; m < NN; ++m) red[m][t] += red[m][t + s];
            }
            __syncthreads();
        }
        if (t < NE) {
            float ys = red[SRC[t]][0], yd = red[DST[t]][0];
            out[H1SZ + t] = 0.5f * (ys + yd) + bv5[0];
        }
    }
}

extern "C" void kernel_launch(void* const* d_in, const int* in_sizes, int n_in,
                              void* d_out, int out_size, void* d_ws, size_t ws_size,
                              hipStream_t stream) {
    const float* x   = (const float*)d_in[0];
    const float* Wa1 = (const float*)d_in[3];
    const float* ba1 = (const float*)d_in[4];
    const float* Wa2 = (const float*)d_in[5];
    const float* ba2 = (const float*)d_in[6];
    const float* Wa5 = (const float*)d_in[7];
    const float* ba5 = (const float*)d_in[8];
    const float* Wv1 = (const float*)d_in[9];
    const float* bv1 = (const float*)d_in[10];
    const float* Wv2 = (const float*)d_in[11];
    const float* bv2 = (const float*)d_in[12];
    const float* Wv5 = (const float*)d_in[13];
    const float* bv5 = (const float*)d_in[14];
    float* out = (float*)d_out;

    float* ws  = (float*)d_ws;
    float* Ax  = ws;                   // 57344
    float* Aa  = ws + 57344;           // 57344
    float* Av  = ws + 114688;          // 57344
    float* Ypa = ws + 172032;          // KB*57344 = 458752
    float* Ypv = ws + 630784;          // KB*57344 = 458752 (total ~4.4 MB)

    prep_x_k<<<16,   256, 0, stream>>>(x, Ax);
    gemm2_k <<<2048, 256, 0, stream>>>(Ax, Wa1, Ypa, Ax, Wv1, Ypv);
    prep2_k <<<32,   256, 0, stream>>>(Ypa, ba1, Aa, Ypv, bv1, Av);
    gemm2_k <<<2048, 256, 0, stream>>>(Aa, Wa2, Ypa, Av, Wv2, Ypv);
    prep2_k <<<32,   256, 0, stream>>>(Ypa, ba2, Aa, Ypv, bv2, Av);
    gemm2_k <<<1024, 256, 0, stream>>>(Aa, Wa5, Ypa, Aa, Wa5, Ypa);
    final_k <<<177,  256, 0, stream>>>(Ypa, ba5, Av, Wv5, bv5, out);
}

// Round 7
// 131.158 us; speedup vs baseline: 2.2121x; 2.2121x over previous
//
#include <hip/hip_runtime.h>

#define F 4096          // feature dim (S_DIM == HID == A_DIM)
#define NE 44
#define NN 14
#define KB 8            // k-split factor
#define KC 512          // k-chunk width per block
#define NKS 32          // ksteps per chunk (KC/16)
#define YPART 57344     // 14*4096, one partial Y buffer
#define H1SZ 180224     // 44*4096

// deterministic edge list from reference _edge_list()
__device__ constexpr int SRC[NE] = {
    0,1,2,3,4,5,6,7,8,9,10,11,12,13,          // fwd ring
    1,2,3,4,5,6,7,8,9,10,11,12,13,0,          // rev ring
    0,1,2,3,4,5,6,7,8,9,10,11,12,13,          // skip-2 ring
    0,7};
__device__ constexpr int DST[NE] = {
    1,2,3,4,5,6,7,8,9,10,11,12,13,0,
    0,1,2,3,4,5,6,7,8,9,10,11,12,13,
    2,3,4,5,6,7,8,9,10,11,12,13,0,1,
    7,0};
// deg: 3 everywhere except nodes 0 and 7 (4)
__device__ constexpr float INVDEG[NN] = {
    0.25f, 1.f/3.f, 1.f/3.f, 1.f/3.f, 1.f/3.f, 1.f/3.f, 1.f/3.f,
    0.25f, 1.f/3.f, 1.f/3.f, 1.f/3.f, 1.f/3.f, 1.f/3.f, 1.f/3.f};

// async global->LDS, 16 B per lane; LDS dest = uniform base + lane*16 (linear)
__device__ __forceinline__ void gload16(const float* g, float* l) {
    __builtin_amdgcn_global_load_lds(
        (const __attribute__((address_space(1))) void*)g,
        (__attribute__((address_space(3))) void*)l, 16, 0, 0);
}

// ---------------- prep: A = node2(edge_features) -------------------------
__global__ __launch_bounds__(256) void prep_x_k(const float* __restrict__ x,
                                                float* __restrict__ Aout) {
    int f = blockIdx.x * 256 + threadIdx.x;   // 16 blocks cover 4096
    float s[NN];
#pragma unroll
    for (int n = 0; n < NN; ++n) s[n] = 0.f;
#pragma unroll
    for (int e = 0; e < NE; ++e) s[DST[e]] += x[e * F + f];
    float node[NN];
#pragma unroll
    for (int n = 0; n < NN; ++n) node[n] = s[n] * INVDEG[n];
    float n2[NN];
#pragma unroll
    for (int n = 0; n < NN; ++n) n2[n] = 0.f;
#pragma unroll
    for (int e = 0; e < NE; ++e) n2[DST[e]] += node[SRC[e]];
#pragma unroll
    for (int m = 0; m < NN; ++m) Aout[m * F + f] = n2[m];
}

// inner layers: edge feat = leaky_relu(0.5*(Y[src]+Y[dst]) + b), Y = sum of KB partials
__device__ __forceinline__ void prep_col(const float* __restrict__ Yp,
                                         const float* __restrict__ b,
                                         float* __restrict__ Aout, int f) {
    float y[NN];
#pragma unroll
    for (int m = 0; m < NN; ++m) {
        float s = 0.f;
#pragma unroll
        for (int kb = 0; kb < KB; ++kb) s += Yp[kb * YPART + m * F + f];
        y[m] = s;
    }
    float bias = b[f];
    float s[NN];
#pragma unroll
    for (int n = 0; n < NN; ++n) s[n] = 0.f;
#pragma unroll
    for (int e = 0; e < NE; ++e) {
        float eh = 0.5f * (y[SRC[e]] + y[DST[e]]) + bias;
        eh = eh > 0.f ? eh : 0.01f * eh;      // leaky_relu(0.01)
        s[DST[e]] += eh;
    }
    float node[NN];
#pragma unroll
    for (int n = 0; n < NN; ++n) node[n] = s[n] * INVDEG[n];
    float n2[NN];
#pragma unroll
    for (int n = 0; n < NN; ++n) n2[n] = 0.f;
#pragma unroll
    for (int e = 0; e < NE; ++e) n2[DST[e]] += node[SRC[e]];
#pragma unroll
    for (int m = 0; m < NN; ++m) Aout[m * F + f] = n2[m];
}

__global__ __launch_bounds__(256) void prep2_k(const float* __restrict__ Yp1,
                                               const float* __restrict__ b1,
                                               float* __restrict__ A1,
                                               const float* __restrict__ Yp2,
                                               const float* __restrict__ b2,
                                               float* __restrict__ A2) {
    int bx = blockIdx.x;
    if (bx < 16) {
        prep_col(Yp1, b1, A1, bx * 256 + threadIdx.x);
    } else {
        prep_col(Yp2, b2, A2, (bx - 16) * 256 + threadIdx.x);
    }
}

// ---------------- GEMM: Y[m][n] = sum_k A[m][k] * W[n][k] ----------------
// A chunk (14 x KC = 28.7 KB) staged once per block via global_load_lds;
// barrier-free k-loop. Lane = (row, k-quarter): wave covers 16 W rows,
// k split 4-way -> acc[14]/lane, W-load = 1 independent float4/kstep
// (16 x 64 B segments/instr), A via 4-addr broadcast ds_read (conflict-free).
// Per branch: 512 blocks = nb(64 row-groups of 64) x kb(8). Fused: 4 blk/CU.
__global__ __launch_bounds__(256, 4) void gemm2_k(const float* __restrict__ A1,
                                                  const float* __restrict__ W1,
                                                  float* __restrict__ Y1,
                                                  const float* __restrict__ A2,
                                                  const float* __restrict__ W2,
                                                  float* __restrict__ Y2,
                                                  int half) {
    __shared__ float Alds[NN * KC];   // 28672 B
    int bx = blockIdx.x;
    const float* A = A1; const float* W = W1; float* Y = Y1;
    if (bx >= half) { A = A2; W = W2; Y = Y2; bx -= half; }
    const int kb = bx & (KB - 1);   // k chunk (512 wide)
    const int nb = bx >> 3;         // 64 row-groups of 64
    const int tid = threadIdx.x;
    const int w   = tid >> 6;
    const int l   = tid & 63;
    const int row = nb * 64 + w * 16 + (l >> 2);  // this lane's W row
    const int kq4 = (l & 3) * 4;                  // k quarter offset
    const int k0  = kb * KC;

    // stage A chunk: 14*KC floats = 1792 float4 = 7 * 256
#pragma unroll
    for (int i = 0; i < 7; ++i) {
        int idx = i * 256 + tid;          // float4 index
        int m   = idx >> 7;               // 128 float4 per row
        int col = (idx & 127) * 4;
        gload16(A + m * F + k0 + col, &Alds[idx * 4]);
    }
    __syncthreads();

    const float* Wrow = W + (size_t)row * F + k0 + kq4;

    float acc[NN];
#pragma unroll
    for (int m = 0; m < NN; ++m) acc[m] = 0.f;

#pragma unroll 4
    for (int ks = 0; ks < NKS; ++ks) {
        float4 wv = *(const float4*)(Wrow + ks * 16);
        const float* al = &Alds[ks * 16 + kq4];
#pragma unroll
        for (int m = 0; m < NN; ++m) {
            float4 a = *(const float4*)(al + m * KC);
            acc[m] += wv.x * a.x + wv.y * a.y + wv.z * a.z + wv.w * a.w;
        }
    }

    // 2-level butterfly over the 4 k-lanes of this row
#pragma unroll
    for (int m = 0; m < NN; ++m) {
        float v = acc[m];
        v += __shfl_xor(v, 1);
        v += __shfl_xor(v, 2);
        acc[m] = v;
    }
    if ((l & 3) == 0) {
#pragma unroll
        for (int m = 0; m < NN; ++m)
            Y[kb * YPART + m * F + row] = acc[m];
    }
}

// ---------------- final: h1 edge expansion + h2 tiny GEMV ----------------
__global__ __launch_bounds__(256) void final_k(const float* __restrict__ Ypa5,
                                               const float* __restrict__ ba5,
                                               const float* __restrict__ Av2,
                                               const float* __restrict__ Wv5,
                                               const float* __restrict__ bv5,
                                               float* __restrict__ out) {
    __shared__ float red[NN][257];
    if (blockIdx.x < 176) {
        int idx4 = (blockIdx.x * 256 + threadIdx.x) * 4;  // 44*4096 elements
        int e = idx4 >> 12, f = idx4 & 4095;
        int se = SRC[e], de = DST[e];
        float4 ys = make_float4(0.f, 0.f, 0.f, 0.f);
        float4 yd = make_float4(0.f, 0.f, 0.f, 0.f);
#pragma unroll
        for (int kb = 0; kb < KB; ++kb) {
            float4 s = *(const float4*)(Ypa5 + kb * YPART + se * F + f);
            float4 d = *(const float4*)(Ypa5 + kb * YPART + de * F + f);
            ys.x += s.x; ys.y += s.y; ys.z += s.z; ys.w += s.w;
            yd.x += d.x; yd.y += d.y; yd.z += d.z; yd.w += d.w;
        }
        float4 bb = *(const float4*)(ba5 + f);
        float4 o;
        o.x = 0.5f * (ys.x + yd.x) + bb.x;
        o.y = 0.5f * (ys.y + yd.y) + bb.y;
        o.z = 0.5f * (ys.z + yd.z) + bb.z;
        o.w = 0.5f * (ys.w + yd.w) + bb.w;
        *(float4*)(out + idx4) = o;
    } else {
        // y[n] = dot(Av2[n], Wv5); h2[e] = 0.5*(y[src]+y[dst]) + bv5
        int t = threadIdx.x;
        float acc[NN];
#pragma unroll
        for (int m = 0; m < NN; ++m) acc[m] = 0.f;
        for (int f = t; f < F; f += 256) {
            float wv = Wv5[f];
#pragma unroll
            for (int m = 0; m < NN; ++m) acc[m] += Av2[m * F + f] * wv;
        }
#pragma unroll
        for (int m = 0; m < NN; ++m) red[m][t] = acc[m];
        __syncthreads();
        for (int s = 128; s > 0; s >>= 1) {
            if (t < s) {
#pragma unroll
                for (int m = 0; m < NN; ++m) red[m][t] += red[m][t + s];
            }
            __syncthreads();
        }
        if (t < NE) {
            float ys = red[SRC[t]][0], yd = red[DST[t]][0];
            out[H1SZ + t] = 0.5f * (ys + yd) + bv5[0];
        }
    }
}

extern "C" void kernel_launch(void* const* d_in, const int* in_sizes, int n_in,
                              void* d_out, int out_size, void* d_ws, size_t ws_size,
                              hipStream_t stream) {
    const float* x   = (const float*)d_in[0];
    const float* Wa1 = (const float*)d_in[3];
    const float* ba1 = (const float*)d_in[4];
    const float* Wa2 = (const float*)d_in[5];
    const float* ba2 = (const float*)d_in[6];
    const float* Wa5 = (const float*)d_in[7];
    const float* ba5 = (const float*)d_in[8];
    const float* Wv1 = (const float*)d_in[9];
    const float* bv1 = (const float*)d_in[10];
    const float* Wv2 = (const float*)d_in[11];
    const float* bv2 = (const float*)d_in[12];
    const float* Wv5 = (const float*)d_in[13];
    const float* bv5 = (const float*)d_in[14];
    float* out = (float*)d_out;

    float* ws  = (float*)d_ws;
    float* Ax  = ws;                   // 57344
    float* Aa  = ws + 57344;           // 57344
    float* Av  = ws + 114688;          // 57344
    float* Ypa = ws + 172032;          // KB*57344 = 458752
    float* Ypv = ws + 630784;          // KB*57344 = 458752 (total ~4.4 MB)

    prep_x_k<<<16,   256, 0, stream>>>(x, Ax);
    gemm2_k <<<1024, 256, 0, stream>>>(Ax, Wa1, Ypa, Ax, Wv1, Ypv, 512);
    prep2_k <<<32,   256, 0, stream>>>(Ypa, ba1, Aa, Ypv, bv1, Av);
    gemm2_k <<<1024, 256, 0, stream>>>(Aa, Wa2, Ypa, Av, Wv2, Ypv, 512);
    prep2_k <<<32,   256, 0, stream>>>(Ypa, ba2, Aa, Ypv, bv2, Av);
    gemm2_k <<<512,  256, 0, stream>>>(Aa, Wa5, Ypa, Aa, Wa5, Ypa, 512);
    final_k <<<177,  256, 0, stream>>>(Ypa, ba5, Av, Wv5, bv5, out);
}

// Round 8
// 110.253 us; speedup vs baseline: 2.6315x; 1.1896x over previous
//
#include <hip/hip_runtime.h>

#define F 4096          // feature dim (S_DIM == HID == A_DIM)
#define NE 44
#define NN 14
#define KB 8            // k-split factor
#define KC 512          // k-chunk width per block
#define NKS 32          // ksteps per chunk (KC/16)
#define RING 8          // W prefetch depth (float4 ring)
#define YPART 57344     // 14*4096, one partial Y buffer
#define H1SZ 180224     // 44*4096

// deterministic edge list from reference _edge_list()
__device__ constexpr int SRC[NE] = {
    0,1,2,3,4,5,6,7,8,9,10,11,12,13,          // fwd ring
    1,2,3,4,5,6,7,8,9,10,11,12,13,0,          // rev ring
    0,1,2,3,4,5,6,7,8,9,10,11,12,13,          // skip-2 ring
    0,7};
__device__ constexpr int DST[NE] = {
    1,2,3,4,5,6,7,8,9,10,11,12,13,0,
    0,1,2,3,4,5,6,7,8,9,10,11,12,13,
    2,3,4,5,6,7,8,9,10,11,12,13,0,1,
    7,0};
// deg: 3 everywhere except nodes 0 and 7 (4)
__device__ constexpr float INVDEG[NN] = {
    0.25f, 1.f/3.f, 1.f/3.f, 1.f/3.f, 1.f/3.f, 1.f/3.f, 1.f/3.f,
    0.25f, 1.f/3.f, 1.f/3.f, 1.f/3.f, 1.f/3.f, 1.f/3.f, 1.f/3.f};

// async global->LDS, 16 B per lane; LDS dest = uniform base + lane*16 (linear)
__device__ __forceinline__ void gload16(const float* g, float* l) {
    __builtin_amdgcn_global_load_lds(
        (const __attribute__((address_space(1))) void*)g,
        (__attribute__((address_space(3))) void*)l, 16, 0, 0);
}

// ---------------- prep: A = node2(edge_features) -------------------------
__global__ __launch_bounds__(256) void prep_x_k(const float* __restrict__ x,
                                                float* __restrict__ Aout) {
    int f = blockIdx.x * 256 + threadIdx.x;   // 16 blocks cover 4096
    float s[NN];
#pragma unroll
    for (int n = 0; n < NN; ++n) s[n] = 0.f;
#pragma unroll
    for (int e = 0; e < NE; ++e) s[DST[e]] += x[e * F + f];
    float node[NN];
#pragma unroll
    for (int n = 0; n < NN; ++n) node[n] = s[n] * INVDEG[n];
    float n2[NN];
#pragma unroll
    for (int n = 0; n < NN; ++n) n2[n] = 0.f;
#pragma unroll
    for (int e = 0; e < NE; ++e) n2[DST[e]] += node[SRC[e]];
#pragma unroll
    for (int m = 0; m < NN; ++m) Aout[m * F + f] = n2[m];
}

// inner layers: edge feat = leaky_relu(0.5*(Y[src]+Y[dst]) + b), Y = sum of KB partials
__device__ __forceinline__ void prep_col(const float* __restrict__ Yp,
                                         const float* __restrict__ b,
                                         float* __restrict__ Aout, int f) {
    float y[NN];
#pragma unroll
    for (int m = 0; m < NN; ++m) {
        float s = 0.f;
#pragma unroll
        for (int kb = 0; kb < KB; ++kb) s += Yp[kb * YPART + m * F + f];
        y[m] = s;
    }
    float bias = b[f];
    float s[NN];
#pragma unroll
    for (int n = 0; n < NN; ++n) s[n] = 0.f;
#pragma unroll
    for (int e = 0; e < NE; ++e) {
        float eh = 0.5f * (y[SRC[e]] + y[DST[e]]) + bias;
        eh = eh > 0.f ? eh : 0.01f * eh;      // leaky_relu(0.01)
        s[DST[e]] += eh;
    }
    float node[NN];
#pragma unroll
    for (int n = 0; n < NN; ++n) node[n] = s[n] * INVDEG[n];
    float n2[NN];
#pragma unroll
    for (int n = 0; n < NN; ++n) n2[n] = 0.f;
#pragma unroll
    for (int e = 0; e < NE; ++e) n2[DST[e]] += node[SRC[e]];
#pragma unroll
    for (int m = 0; m < NN; ++m) Aout[m * F + f] = n2[m];
}

__global__ __launch_bounds__(256) void prep2_k(const float* __restrict__ Yp1,
                                               const float* __restrict__ b1,
                                               float* __restrict__ A1,
                                               const float* __restrict__ Yp2,
                                               const float* __restrict__ b2,
                                               float* __restrict__ A2) {
    int bx = blockIdx.x;
    if (bx < 16) {
        prep_col(Yp1, b1, A1, bx * 256 + threadIdx.x);
    } else {
        prep_col(Yp2, b2, A2, (bx - 16) * 256 + threadIdx.x);
    }
}

// ---------------- GEMM: Y[m][n] = sum_k A[m][k] * W[n][k] ----------------
// R7 structure (A chunk in LDS via global_load_lds, barrier-free k-loop,
// lane = (row, k-quarter)) + NEW: explicit 8-deep register ring for the W
// stream (static indices, fully unrolled) -> 8 W-loads in flight per wave.
// 16 waves/CU x 8 x 64 B = 8 KB/CU in flight -> ~5.6 TB/s Little's-law cap.
__global__ __launch_bounds__(256, 4) void gemm2_k(const float* __restrict__ A1,
                                                  const float* __restrict__ W1,
                                                  float* __restrict__ Y1,
                                                  const float* __restrict__ A2,
                                                  const float* __restrict__ W2,
                                                  float* __restrict__ Y2,
                                                  int half) {
    __shared__ float Alds[NN * KC];   // 28672 B
    int bx = blockIdx.x;
    const float* A = A1; const float* W = W1; float* Y = Y1;
    if (bx >= half) { A = A2; W = W2; Y = Y2; bx -= half; }
    const int kb = bx & (KB - 1);   // k chunk (512 wide)
    const int nb = bx >> 3;         // 64 row-groups of 64
    const int tid = threadIdx.x;
    const int w   = tid >> 6;
    const int l   = tid & 63;
    const int row = nb * 64 + w * 16 + (l >> 2);  // this lane's W row
    const int kq4 = (l & 3) * 4;                  // k quarter offset
    const int k0  = kb * KC;

    // stage A chunk: 14*KC floats = 1792 float4 = 7 * 256
#pragma unroll
    for (int i = 0; i < 7; ++i) {
        int idx = i * 256 + tid;          // float4 index
        int m   = idx >> 7;               // 128 float4 per row
        int col = (idx & 127) * 4;
        gload16(A + m * F + k0 + col, &Alds[idx * 4]);
    }

    const float* Wrow = W + (size_t)row * F + k0 + kq4;

    // prime the 8-deep W ring while A staging is in flight
    float4 wv[RING];
#pragma unroll
    for (int j = 0; j < RING; ++j)
        wv[j] = *(const float4*)(Wrow + j * 16);

    __syncthreads();

    float acc[NN];
#pragma unroll
    for (int m = 0; m < NN; ++m) acc[m] = 0.f;

#pragma unroll
    for (int ks = 0; ks < NKS; ++ks) {    // fully unrolled: ring idx static
        float4 wq = wv[ks & (RING - 1)];
        if (ks + RING < NKS)
            wv[ks & (RING - 1)] = *(const float4*)(Wrow + (ks + RING) * 16);
        const float* al = &Alds[ks * 16 + kq4];
#pragma unroll
        for (int m = 0; m < NN; ++m) {
            float4 a = *(const float4*)(al + m * KC);
            acc[m] += wq.x * a.x + wq.y * a.y + wq.z * a.z + wq.w * a.w;
        }
    }

    // 2-level butterfly over the 4 k-lanes of this row
#pragma unroll
    for (int m = 0; m < NN; ++m) {
        float v = acc[m];
        v += __shfl_xor(v, 1);
        v += __shfl_xor(v, 2);
        acc[m] = v;
    }
    if ((l & 3) == 0) {
#pragma unroll
        for (int m = 0; m < NN; ++m)
            Y[kb * YPART + m * F + row] = acc[m];
    }
}

// ---------------- final: h1 edge expansion + h2 tiny GEMV ----------------
__global__ __launch_bounds__(256) void final_k(const float* __restrict__ Ypa5,
                                               const float* __restrict__ ba5,
                                               const float* __restrict__ Av2,
                                               const float* __restrict__ Wv5,
                                               const float* __restrict__ bv5,
                                               float* __restrict__ out) {
    __shared__ float red[NN][257];
    if (blockIdx.x < 176) {
        int idx4 = (blockIdx.x * 256 + threadIdx.x) * 4;  // 44*4096 elements
        int e = idx4 >> 12, f = idx4 & 4095;
        int se = SRC[e], de = DST[e];
        float4 ys = make_float4(0.f, 0.f, 0.f, 0.f);
        float4 yd = make_float4(0.f, 0.f, 0.f, 0.f);
#pragma unroll
        for (int kb = 0; kb < KB; ++kb) {
            float4 s = *(const float4*)(Ypa5 + kb * YPART + se * F + f);
            float4 d = *(const float4*)(Ypa5 + kb * YPART + de * F + f);
            ys.x += s.x; ys.y += s.y; ys.z += s.z; ys.w += s.w;
            yd.x += d.x; yd.y += d.y; yd.z += d.z; yd.w += d.w;
        }
        float4 bb = *(const float4*)(ba5 + f);
        float4 o;
        o.x = 0.5f * (ys.x + yd.x) + bb.x;
        o.y = 0.5f * (ys.y + yd.y) + bb.y;
        o.z = 0.5f * (ys.z + yd.z) + bb.z;
        o.w = 0.5f * (ys.w + yd.w) + bb.w;
        *(float4*)(out + idx4) = o;
    } else {
        // y[n] = dot(Av2[n], Wv5); h2[e] = 0.5*(y[src]+y[dst]) + bv5
        int t = threadIdx.x;
        float acc[NN];
#pragma unroll
        for (int m = 0; m < NN; ++m) acc[m] = 0.f;
        for (int f = t; f < F; f += 256) {
            float wv = Wv5[f];
#pragma unroll
            for (int m = 0; m < NN; ++m) acc[m] += Av2[m * F + f] * wv;
        }
#pragma unroll
        for (int m = 0; m < NN; ++m) red[m][t] = acc[m];
        __syncthreads();
        for (int s = 128; s > 0; s >>= 1) {
            if (t < s) {
#pragma unroll
                for (int m = 0; m < NN; ++m) red[m][t] += red[m][t + s];
            }
            __syncthreads();
        }
        if (t < NE) {
            float ys = red[SRC[t]][0], yd = red[DST[t]][0];
            out[H1SZ + t] = 0.5f * (ys + yd) + bv5[0];
        }
    }
}

extern "C" void kernel_launch(void* const* d_in, const int* in_sizes, int n_in,
                              void* d_out, int out_size, void* d_ws, size_t ws_size,
                              hipStream_t stream) {
    const float* x   = (const float*)d_in[0];
    const float* Wa1 = (const float*)d_in[3];
    const float* ba1 = (const float*)d_in[4];
    const float* Wa2 = (const float*)d_in[5];
    const float* ba2 = (const float*)d_in[6];
    const float* Wa5 = (const float*)d_in[7];
    const float* ba5 = (const float*)d_in[8];
    const float* Wv1 = (const float*)d_in[9];
    const float* bv1 = (const float*)d_in[10];
    const float* Wv2 = (const float*)d_in[11];
    const float* bv2 = (const float*)d_in[12];
    const float* Wv5 = (const float*)d_in[13];
    const float* bv5 = (const float*)d_in[14];
    float* out = (float*)d_out;

    float* ws  = (float*)d_ws;
    float* Ax  = ws;                   // 57344
    float* Aa  = ws + 57344;           // 57344
    float* Av  = ws + 114688;          // 57344
    float* Ypa = ws + 172032;          // KB*57344 = 458752
    float* Ypv = ws + 630784;          // KB*57344 = 458752 (total ~4.4 MB)

    prep_x_k<<<16,   256, 0, stream>>>(x, Ax);
    gemm2_k <<<1024, 256, 0, stream>>>(Ax, Wa1, Ypa, Ax, Wv1, Ypv, 512);
    prep2_k <<<32,   256, 0, stream>>>(Ypa, ba1, Aa, Ypv, bv1, Av);
    gemm2_k <<<1024, 256, 0, stream>>>(Aa, Wa2, Ypa, Av, Wv2, Ypv, 512);
    prep2_k <<<32,   256, 0, stream>>>(Ypa, ba2, Aa, Ypv, bv2, Av);
    gemm2_k <<<512,  256, 0, stream>>>(Aa, Wa5, Ypa, Aa, Wa5, Ypa, 512);
    final_k <<<177,  256, 0, stream>>>(Ypa, ba5, Av, Wv5, bv5, out);
}